// Round 10
// baseline (493.869 us; speedup 1.0000x reference)
//
#include <hip/hip_runtime.h>
#include <stdint.h>

typedef unsigned short u16;
typedef __attribute__((ext_vector_type(8))) u16   u16x8;
typedef __attribute__((ext_vector_type(4))) u16   u16x4;
typedef __attribute__((ext_vector_type(8))) __bf16 bf16x8;
typedef __attribute__((ext_vector_type(4))) float  f32x4;

__device__ __forceinline__ u16 f2bf(float f) {
  union { float f; unsigned u; } x; x.f = f;
  unsigned r = x.u + 0x7fffu + ((x.u >> 16) & 1u);   // RNE
  return (u16)(r >> 16);
}
__device__ __forceinline__ float bf2f(u16 h) {
  union { unsigned u; float f; } x; x.u = ((unsigned)h) << 16;
  return x.f;
}
__device__ __forceinline__ float fexp2(float x) {
#if __has_builtin(__builtin_amdgcn_exp2f)
  return __builtin_amdgcn_exp2f(x);
#else
  return __expf(x * 0.69314718055994531f);
#endif
}
// async global->LDS, 16B per lane; LDS dest = uniform base + lane*16
__device__ __forceinline__ void gload_lds16(const void* g, void* l) {
  __builtin_amdgcn_global_load_lds(
      (__attribute__((address_space(1))) void*)(void*)g,
      (__attribute__((address_space(3))) void*)l, 16, 0, 0);
}
__device__ __forceinline__ bf16x8 ldfrag(const u16* p) {
  return __builtin_bit_cast(bf16x8, *(const u16x8*)p);
}
#define MFMA_BF16(a, b, c) __builtin_amdgcn_mfma_f32_16x16x32_bf16(a, b, c, 0, 0, 0)

// ---------------- elementwise fp32 -> bf16 ----------------
__global__ __launch_bounds__(256) void k_f32_to_bf16(const float* __restrict__ in,
                                                     u16* __restrict__ out, int n) {
  int i = (blockIdx.x * 256 + threadIdx.x) * 4;
  if (i >= n) return;
  float4 v = *(const float4*)(in + i);
  u16x4 o; o.x = f2bf(v.x); o.y = f2bf(v.y); o.z = f2bf(v.z); o.w = f2bf(v.w);
  *(u16x4*)(out + i) = o;
}

// ---------------- transpose fp32 (R x C) -> bf16 (C x R) ----------------
__global__ __launch_bounds__(256) void k_transpose_bf16(const float* __restrict__ in,
                                                        u16* __restrict__ out,
                                                        int R, int C) {
  __shared__ float tile[32][33];
  int c0 = blockIdx.x * 32, r0 = blockIdx.y * 32;
  int tx = threadIdx.x, ty = threadIdx.y;  // block (32,8)
#pragma unroll
  for (int i = 0; i < 32; i += 8)
    tile[ty + i][tx] = in[(size_t)(r0 + ty + i) * C + c0 + tx];
  __syncthreads();
#pragma unroll
  for (int i = 0; i < 32; i += 8)
    out[(size_t)(c0 + ty + i) * R + r0 + tx] = f2bf(tile[tx][ty + i]);
}

// ---------------- QKV GEMM: A(8192x1024) @ Wt(3072x1024)^T, scatter epilogue ----
// Q,K -> [b*16+h][s][d] bf16 ; V -> transposed + s-interleaved:
//   Vt[bh][d][s'] with s' = (s & ~31) | ((s&15)<<1) | ((s>>4)&1)
// BK=64, single 32KB buffer, 2-barrier loop, XOR-swizzled [128][64] tiles.
__global__ __launch_bounds__(256) void k_gemm_qkv(const u16* __restrict__ A,
                                                  const u16* __restrict__ Bt,
                                                  u16* __restrict__ Q,
                                                  u16* __restrict__ Kb,
                                                  u16* __restrict__ Vt) {
  const int K = 1024;
  __shared__ u16 As[128 * 64];   // 16 KB, swizzled
  __shared__ u16 Bs[128 * 64];   // 16 KB, swizzled
  int tid = threadIdx.x;
  int wave = tid >> 6, lane = tid & 63, quad = lane >> 4, l15 = lane & 15;
  int m0 = blockIdx.y * 128, n0 = blockIdx.x * 128;
  int wm = (wave >> 1) * 64, wn = (wave & 1) * 64;
  f32x4 acc[4][4] = {};
  const u16* Ag = A + (size_t)m0 * K;
  const u16* Bg = Bt + (size_t)n0 * K;
  int klr = lane >> 3, klc = lane & 7;   // row-in-8, k-chunk

  for (int k0 = 0; k0 < K; k0 += 64) {
    if (k0) __syncthreads();             // everyone done reading prev tile
#pragma unroll
    for (int i = 0; i < 4; i++) {
      int c = wave * 4 + i;              // 16 chunks x 8 rows = 128 rows
      gload_lds16(Ag + (size_t)(c * 8 + klr) * K + k0 + (klc ^ klr) * 8, &As[c * 512]);
      gload_lds16(Bg + (size_t)(c * 8 + klr) * K + k0 + (klc ^ klr) * 8, &Bs[c * 512]);
    }
    __syncthreads();                     // drains vm/lgkm: tile visible
#pragma unroll
    for (int ks = 0; ks < 2; ks++) {
      bf16x8 af[4], bf[4];
#pragma unroll
      for (int mi = 0; mi < 4; mi++)
        af[mi] = ldfrag(&As[(wm + mi * 16 + l15) * 64 + (((ks * 4 + quad) ^ (l15 & 7)) << 3)]);
#pragma unroll
      for (int ni = 0; ni < 4; ni++)
        bf[ni] = ldfrag(&Bs[(wn + ni * 16 + l15) * 64 + (((ks * 4 + quad) ^ (l15 & 7)) << 3)]);
#pragma unroll
      for (int mi = 0; mi < 4; mi++)
#pragma unroll
        for (int ni = 0; ni < 4; ni++)
          acc[mi][ni] = MFMA_BF16(af[mi], bf[ni], acc[mi][ni]);
    }
  }
  int sec = n0 >> 10;  // uniform per block: 0=q 1=k 2=v
#pragma unroll
  for (int mi = 0; mi < 4; mi++) {
    int rowb = m0 + wm + mi * 16 + quad * 4;
#pragma unroll
    for (int ni = 0; ni < 4; ni++) {
      int col = n0 + wn + ni * 16 + l15;
      int cc = col & 1023, h = cc >> 6, d = cc & 63;
#pragma unroll
      for (int r = 0; r < 4; r++) {
        int rg = rowb + r, b = rg >> 12, s = rg & 4095;
        u16 v = f2bf(acc[mi][ni][r]);
        size_t bh = (size_t)(b * 16 + h);
        if (sec == 0)      Q [(bh * 4096 + s) * 64 + d] = v;
        else if (sec == 1) Kb[(bh * 4096 + s) * 64 + d] = v;
        else {
          int sp = (s & ~31) | (((s & 15) << 1) | ((s >> 4) & 1));
          Vt[(bh * 64 + d) * 4096 + sp] = v;
        }
      }
    }
  }
}

// ---------------- RMSNorm + RoPE, in place, 16 lanes x 4 elems per row -------
__global__ __launch_bounds__(256) void k_rms_rope(u16* __restrict__ buf,
                                                  const float* __restrict__ gamma,
                                                  const float* __restrict__ cosb,
                                                  const float* __restrict__ sinb,
                                                  float scale) {
  int rid = blockIdx.x * 16 + (threadIdx.x >> 4);  // row over B*NH*S
  int l = threadIdx.x & 15;                        // 4 elems per lane
  int s = rid & 4095;
  int d0 = l * 4;
  size_t idx = (size_t)rid * 64 + d0;
  u16x4 xv = *(const u16x4*)(buf + idx);
  float x0 = bf2f(xv.x), x1 = bf2f(xv.y), x2 = bf2f(xv.z), x3 = bf2f(xv.w);
  float ss = x0 * x0 + x1 * x1 + x2 * x2 + x3 * x3;
#pragma unroll
  for (int off = 1; off < 16; off <<= 1) ss += __shfl_xor(ss, off);
  float rms = rsqrtf(ss * (1.0f / 64.0f) + 1e-6f);
  float4 g = *(const float4*)(gamma + d0);
  float n0 = x0 * rms * g.x, n1 = x1 * rms * g.y, n2 = x2 * rms * g.z, n3 = x3 * rms * g.w;
  float p0 = __shfl_xor(n0, 8), p1 = __shfl_xor(n1, 8);
  float p2 = __shfl_xor(n2, 8), p3 = __shfl_xor(n3, 8);
  float sgn = (l < 8) ? -1.f : 1.f;
  float4 c = *(const float4*)(cosb + s * 64 + d0);
  float4 sn = *(const float4*)(sinb + s * 64 + d0);
  u16x4 o;
  o.x = f2bf((n0 * c.x + sgn * p0 * sn.x) * scale);
  o.y = f2bf((n1 * c.y + sgn * p1 * sn.y) * scale);
  o.z = f2bf((n2 * c.z + sgn * p2 * sn.z) * scale);
  o.w = f2bf((n3 * c.w + sgn * p3 * sn.w) * scale);
  *(u16x4*)(buf + idx) = o;
}

// ---------------- causal flash attention -----------------------------------
// Q,K: [bh][s][d] bf16 ; Vt: [bh][d][s'] bf16 (s-interleaved, see k_gemm_qkv)
// Round-10: 256-row tile, 4 waves x 64 q-rows (halved LDS traffic per row,
// round 9) AT 2 waves/SIMD (round 9's missing ingredient):
//   VGPR 256 allows 2 waves/SIMD; the blocker was LDS (84 KB). V is now
//   SINGLE-buffered with a counted-vmcnt B2 (T4): at iter top issue V[j]
//   FIRST, then the K[j+1] prefetch; before PV wait vmcnt(4) -- in-order
//   vmcnt retires the 4 oldest (= V) loads while K[j+1] stays in flight
//   across the B2 barrier (last iter: vmcnt(0), no prefetch outstanding).
//   V's HBM latency hides under QK^T+softmax. LDS = 32+16+20 = 68 KB ->
//   2 blocks/CU = 8 waves/CU. Complementary tiles (15-t, t): 34 iters/block.
// FIXED-MAX softmax: |score|*log2e/8 < 47 provably; shift folded into QK^T
// accumulator init; row-sum via ones-MFMA; packed-P via v_cvt_pk_bf16_f32
// with pre-interleaved V.
__device__ __forceinline__ void stage_k(const u16* Kg0, int kj, u16* Kbuf,
                                        int wave, int klr, int klc) {
  const u16* Kg = Kg0 + (size_t)kj * 128 * 64;
#pragma unroll
  for (int i = 0; i < 4; i++) {
    int c = wave * 4 + i;
    gload_lds16(Kg + (size_t)(c * 8 + klr) * 64 + (klc ^ klr) * 8, Kbuf + c * 512);
  }
}
__device__ __forceinline__ void stage_v(const u16* Vg0, int kj, u16* Vbuf,
                                        int wave, int quad, int l15) {
  const u16* Vg = Vg0 + kj * 128;
#pragma unroll
  for (int i = 0; i < 4; i++) {
    int c = wave * 4 + i;
    int vr = c * 4 + quad;
    gload_lds16(Vg + (size_t)vr * 4096 + (l15 ^ (vr & 15)) * 8, Vbuf + c * 512);
  }
}

__global__ __launch_bounds__(256, 2) void k_attn(const u16* __restrict__ Qb,
                                                 const u16* __restrict__ Kg_all,
                                                 const u16* __restrict__ Vtb,
                                                 u16* __restrict__ Ob) {
  __shared__ u16 Ks[2][128 * 64];   // 32 KB (double buffer)
  __shared__ u16 Vts[64 * 128];     // 16 KB (single buffer, counted-vmcnt B2)
  __shared__ u16 Ps[4][64 * 40];    // 20 KB, wave-private, stride 40
  const int PSTR = 40;
  int t = blockIdx.x, bhi = blockIdx.y;
  int tid = threadIdx.x, wave = tid >> 6, lane = tid & 63, quad = lane >> 4, l15 = lane & 15;
  const u16* Kg0 = Kg_all + (size_t)bhi * 4096 * 64;
  const u16* Vg0 = Vtb + (size_t)bhi * 64 * 4096;
  u16* Pw = Ps[wave];
  int klr = lane >> 3, klc = lane & 7;
  int b = bhi >> 4, h = bhi & 15;

  u16x8 ou;
#pragma unroll
  for (int i = 0; i < 8; i++) ou[i] = 0x3F80;       // bf16 1.0
  bf16x8 ones = __builtin_bit_cast(bf16x8, ou);
  const f32x4 minit = {-47.f, -47.f, -47.f, -47.f}; // fixed softmax max

#pragma unroll 1
  for (int tt = 0; tt < 2; tt++) {
    int qi = (tt == 0) ? (15 - t) : t;   // 256-row tile index, 0..15
    const u16* Qg = Qb + ((size_t)bhi * 4096 + qi * 256) * 64;
    bf16x8 aq[4][2];
#pragma unroll
    for (int mi = 0; mi < 4; mi++)
#pragma unroll
      for (int ks = 0; ks < 2; ks++)
        aq[mi][ks] = ldfrag(Qg + (size_t)(wave * 64 + mi * 16 + l15) * 64 + ks * 32 + quad * 8);
    f32x4 oacc[4][4] = {};
    f32x4 lacc[4] = {};

    if (tt) __builtin_amdgcn_s_barrier();  // all waves done with prev-tile buffers
    stage_k(Kg0, 0, Ks[0], wave, klr, klc);
    int kjmax = 2 * qi + 1;

#pragma unroll 1
    for (int kj = 0; kj <= kjmax; kj++) {
      int cur = kj & 1;
      // B1: drain K[kj] (issued a full iter ago; only K outstanding here),
      // barrier -> K[cur] visible to all, V buffer free (PV of kj-1 done).
      asm volatile("s_waitcnt vmcnt(0)" ::: "memory");
      __builtin_amdgcn_s_barrier();
      stage_v(Vg0, kj, Vts, wave, quad, l15);     // V FIRST (oldest in queue)
      asm volatile("" ::: "memory");              // pin issue order V -> K
      if (kj < kjmax)
        stage_k(Kg0, kj + 1, Ks[cur ^ 1], wave, klr, klc);
      // S = Q K^T - 47 (q pre-scaled by log2e/8 -> base-2 domain)
      f32x4 sa[4][8];
#pragma unroll
      for (int mi = 0; mi < 4; mi++)
#pragma unroll
        for (int nb = 0; nb < 8; nb++) sa[mi][nb] = minit;
      __builtin_amdgcn_s_setprio(1);
#pragma unroll
      for (int ks = 0; ks < 2; ks++) {
#pragma unroll
        for (int nb = 0; nb < 8; nb++) {
          bf16x8 bk = ldfrag(&Ks[cur][(nb * 16 + l15) * 64 + (((ks * 4 + quad) ^ (l15 & 7)) << 3)]);
#pragma unroll
          for (int mi = 0; mi < 4; mi++)
            sa[mi][nb] = MFMA_BF16(aq[mi][ks], bk, sa[mi][nb]);
        }
      }
      __builtin_amdgcn_s_setprio(0);
      if (kj >= 2 * qi) {  // causal mask on the two diagonal-band k-blocks
        int d128 = (kj - 2 * qi) * 128;
#pragma unroll
        for (int mi = 0; mi < 4; mi++)
#pragma unroll
          for (int nb = 0; nb < 8; nb++)
#pragma unroll
            for (int r = 0; r < 4; r++) {
              int rowi = wave * 64 + mi * 16 + quad * 4 + r;
              int coli = nb * 16 + l15;
              if (coli > rowi - d128) sa[mi][nb][r] = -1e30f;
            }
      }
      // p = exp2(s - 47); no max tracking, no rescale
#pragma unroll
      for (int mi = 0; mi < 4; mi++)
#pragma unroll
        for (int nb = 0; nb < 8; nb++)
#pragma unroll
          for (int r = 0; r < 4; r++)
            sa[mi][nb][r] = fexp2(sa[mi][nb][r]);
      // B2: wait only for the 4 oldest loads (= our V); K[kj+1] stays in
      // flight across the barrier. Last iter has no prefetch -> vmcnt(0).
      if (kj < kjmax) asm volatile("s_waitcnt vmcnt(4)" ::: "memory");
      else            asm volatile("s_waitcnt vmcnt(0)" ::: "memory");
      __builtin_amdgcn_s_barrier();
      // O += P V, 32-wide k chunks; packed-P via wave-private LDS (no barrier)
#pragma unroll
      for (int ks = 0; ks < 4; ks++) {
        bf16x8 ap[4];
#pragma unroll
        for (int mi = 0; mi < 4; mi++) {
#pragma unroll
          for (int r = 0; r < 4; r++) {
            int prow = mi * 16 + quad * 4 + r;
            float lo = sa[mi][2 * ks][r], hi = sa[mi][2 * ks + 1][r];
            uint32_t pk;
            asm("v_cvt_pk_bf16_f32 %0, %1, %2" : "=v"(pk) : "v"(lo), "v"(hi));
            *(uint32_t*)&Pw[prow * PSTR + 2 * l15] = pk;
          }
          ap[mi] = ldfrag(&Pw[(mi * 16 + l15) * PSTR + quad * 8]);
        }
        __builtin_amdgcn_s_setprio(1);
#pragma unroll
        for (int oni = 0; oni < 4; oni++) {
          bf16x8 bv = ldfrag(&Vts[(oni * 16 + l15) * 128 + (((ks * 4 + quad) ^ l15) << 3)]);
#pragma unroll
          for (int mi = 0; mi < 4; mi++)
            oacc[mi][oni] = MFMA_BF16(ap[mi], bv, oacc[mi][oni]);
        }
#pragma unroll
        for (int mi = 0; mi < 4; mi++)
          lacc[mi] = MFMA_BF16(ap[mi], ones, lacc[mi]);
        __builtin_amdgcn_s_setprio(0);
      }
    }
    // epilogue: O tile to global (normalize by row sum)
#pragma unroll
    for (int mi = 0; mi < 4; mi++)
#pragma unroll
      for (int oni = 0; oni < 4; oni++)
#pragma unroll
        for (int r = 0; r < 4; r++) {
          float v = oacc[mi][oni][r] / lacc[mi][r];
          int srow = qi * 256 + wave * 64 + mi * 16 + quad * 4 + r;
          int d = oni * 16 + l15;
          Ob[((size_t)(b * 4096 + srow)) * 1024 + h * 64 + d] = f2bf(v);
        }
  }
}

// ---------------- out GEMM: A(8192x1024) @ Wot(1024x1024)^T -> fp32 ----------
// BK=64 single-buffer swizzled, same as k_gemm_qkv.
__global__ __launch_bounds__(256) void k_gemm_out(const u16* __restrict__ A,
                                                  const u16* __restrict__ Bt,
                                                  float* __restrict__ C) {
  const int K = 1024, N = 1024;
  __shared__ u16 As[128 * 64];
  __shared__ u16 Bs[128 * 64];
  int tid = threadIdx.x;
  int wave = tid >> 6, lane = tid & 63, quad = lane >> 4, l15 = lane & 15;
  int m0 = blockIdx.y * 128, n0 = blockIdx.x * 128;
  int wm = (wave >> 1) * 64, wn = (wave & 1) * 64;
  f32x4 acc[4][4] = {};
  const u16* Ag = A + (size_t)m0 * K;
  const u16* Bg = Bt + (size_t)n0 * K;
  int klr = lane >> 3, klc = lane & 7;

  for (int k0 = 0; k0 < K; k0 += 64) {
    if (k0) __syncthreads();
#pragma unroll
    for (int i = 0; i < 4; i++) {
      int c = wave * 4 + i;
      gload_lds16(Ag + (size_t)(c * 8 + klr) * K + k0 + (klc ^ klr) * 8, &As[c * 512]);
      gload_lds16(Bg + (size_t)(c * 8 + klr) * K + k0 + (klc ^ klr) * 8, &Bs[c * 512]);
    }
    __syncthreads();
#pragma unroll
    for (int ks = 0; ks < 2; ks++) {
      bf16x8 af[4], bf[4];
#pragma unroll
      for (int mi = 0; mi < 4; mi++)
        af[mi] = ldfrag(&As[(wm + mi * 16 + l15) * 64 + (((ks * 4 + quad) ^ (l15 & 7)) << 3)]);
#pragma unroll
      for (int ni = 0; ni < 4; ni++)
        bf[ni] = ldfrag(&Bs[(wn + ni * 16 + l15) * 64 + (((ks * 4 + quad) ^ (l15 & 7)) << 3)]);
#pragma unroll
      for (int mi = 0; mi < 4; mi++)
#pragma unroll
        for (int ni = 0; ni < 4; ni++)
          acc[mi][ni] = MFMA_BF16(af[mi], bf[ni], acc[mi][ni]);
    }
  }
#pragma unroll
  for (int mi = 0; mi < 4; mi++) {
    int rowb = m0 + wm + mi * 16 + quad * 4;
#pragma unroll
    for (int ni = 0; ni < 4; ni++) {
      int col = n0 + wn + ni * 16 + l15;
#pragma unroll
      for (int r = 0; r < 4; r++)
        C[(size_t)(rowb + r) * N + col] = acc[mi][ni][r];
    }
  }
}

extern "C" void kernel_launch(void* const* d_in, const int* in_sizes, int n_in,
                              void* d_out, int out_size, void* d_ws, size_t ws_size,
                              hipStream_t stream) {
  (void)in_sizes; (void)n_in; (void)out_size; (void)ws_size;
  const float* hs   = (const float*)d_in[0];  // (2,4096,1024)
  const float* cosb = (const float*)d_in[1];  // (1,4096,64)
  const float* sinb = (const float*)d_in[2];
  const float* wqkv = (const float*)d_in[3];  // (1024,3072)
  const float* wo   = (const float*)d_in[4];  // (1024,1024)
  const float* gq   = (const float*)d_in[5];
  const float* gk   = (const float*)d_in[6];
  float* out = (float*)d_out;

  char* ws = (char*)d_ws;
  u16* Xb    = (u16*)(ws);              // 16,777,216 B
  u16* Wqkvt = (u16*)(ws + 16777216);   //  6,291,456 B
  u16* Wot   = (u16*)(ws + 23068672);   //  2,097,152 B
  u16* Qb    = (u16*)(ws + 25165824);   // 16,777,216 B
  u16* Kb    = (u16*)(ws + 41943040);   // 16,777,216 B
  u16* Vtb   = (u16*)(ws + 58720256);   // 16,777,216 B
  u16* Ab    = (u16*)(ws + 75497472);   // 16,777,216 B  (total ~92.3 MB)

  k_f32_to_bf16<<<8192, 256, 0, stream>>>(hs, Xb, 8388608);
  k_transpose_bf16<<<dim3(96, 32), dim3(32, 8), 0, stream>>>(wqkv, Wqkvt, 1024, 3072);
  k_transpose_bf16<<<dim3(32, 32), dim3(32, 8), 0, stream>>>(wo, Wot, 1024, 1024);
  k_gemm_qkv<<<dim3(24, 64), 256, 0, stream>>>(Xb, Wqkvt, Qb, Kb, Vtb);
  // Q scaled by 1/sqrt(hd) * log2(e): softmax runs in base-2 domain
  k_rms_rope<<<8192, 256, 0, stream>>>(Qb, gq, cosb, sinb, 0.18033688011112042f);
  k_rms_rope<<<8192, 256, 0, stream>>>(Kb, gk, cosb, sinb, 1.0f);
  k_attn<<<dim3(8, 32), 256, 0, stream>>>(Qb, Kb, Vtb, Ab);
  k_gemm_out<<<dim3(8, 64), 256, 0, stream>>>(Ab, Wot, out);
}

// Round 11
// 374.419 us; speedup vs baseline: 1.3190x; 1.3190x over previous
//
#include <hip/hip_runtime.h>
#include <stdint.h>

typedef unsigned short u16;
typedef __attribute__((ext_vector_type(8))) u16   u16x8;
typedef __attribute__((ext_vector_type(4))) u16   u16x4;
typedef __attribute__((ext_vector_type(8))) __bf16 bf16x8;
typedef __attribute__((ext_vector_type(4))) float  f32x4;

__device__ __forceinline__ u16 f2bf(float f) {
  union { float f; unsigned u; } x; x.f = f;
  unsigned r = x.u + 0x7fffu + ((x.u >> 16) & 1u);   // RNE
  return (u16)(r >> 16);
}
__device__ __forceinline__ float bf2f(u16 h) {
  union { unsigned u; float f; } x; x.u = ((unsigned)h) << 16;
  return x.f;
}
__device__ __forceinline__ float fexp2(float x) {
#if __has_builtin(__builtin_amdgcn_exp2f)
  return __builtin_amdgcn_exp2f(x);
#else
  return __expf(x * 0.69314718055994531f);
#endif
}
// async global->LDS, 16B per lane; LDS dest = uniform base + lane*16
__device__ __forceinline__ void gload_lds16(const void* g, void* l) {
  __builtin_amdgcn_global_load_lds(
      (__attribute__((address_space(1))) void*)(void*)g,
      (__attribute__((address_space(3))) void*)l, 16, 0, 0);
}
__device__ __forceinline__ bf16x8 ldfrag(const u16* p) {
  return __builtin_bit_cast(bf16x8, *(const u16x8*)p);
}
#define MFMA_BF16(a, b, c) __builtin_amdgcn_mfma_f32_16x16x32_bf16(a, b, c, 0, 0, 0)

// ---------------- elementwise fp32 -> bf16 ----------------
__global__ __launch_bounds__(256) void k_f32_to_bf16(const float* __restrict__ in,
                                                     u16* __restrict__ out, int n) {
  int i = (blockIdx.x * 256 + threadIdx.x) * 4;
  if (i >= n) return;
  float4 v = *(const float4*)(in + i);
  u16x4 o; o.x = f2bf(v.x); o.y = f2bf(v.y); o.z = f2bf(v.z); o.w = f2bf(v.w);
  *(u16x4*)(out + i) = o;
}

// ---------------- transpose fp32 (R x C) -> bf16 (C x R) ----------------
__global__ __launch_bounds__(256) void k_transpose_bf16(const float* __restrict__ in,
                                                        u16* __restrict__ out,
                                                        int R, int C) {
  __shared__ float tile[32][33];
  int c0 = blockIdx.x * 32, r0 = blockIdx.y * 32;
  int tx = threadIdx.x, ty = threadIdx.y;  // block (32,8)
#pragma unroll
  for (int i = 0; i < 32; i += 8)
    tile[ty + i][tx] = in[(size_t)(r0 + ty + i) * C + c0 + tx];
  __syncthreads();
#pragma unroll
  for (int i = 0; i < 32; i += 8)
    out[(size_t)(c0 + ty + i) * R + r0 + tx] = f2bf(tile[tx][ty + i]);
}

// ---------------- QKV GEMM: A(8192x1024) @ Wt(3072x1024)^T, scatter epilogue ----
// Q,K -> [b*16+h][s][d] bf16 ; V -> transposed + s-interleaved:
//   Vt[bh][d][s'] with s' = (s & ~31) | ((s&15)<<1) | ((s>>4)&1)
// BK=64, single 32KB buffer, 2-barrier loop, XOR-swizzled [128][64] tiles.
__global__ __launch_bounds__(256) void k_gemm_qkv(const u16* __restrict__ A,
                                                  const u16* __restrict__ Bt,
                                                  u16* __restrict__ Q,
                                                  u16* __restrict__ Kb,
                                                  u16* __restrict__ Vt) {
  const int K = 1024;
  __shared__ u16 As[128 * 64];   // 16 KB, swizzled
  __shared__ u16 Bs[128 * 64];   // 16 KB, swizzled
  int tid = threadIdx.x;
  int wave = tid >> 6, lane = tid & 63, quad = lane >> 4, l15 = lane & 15;
  int m0 = blockIdx.y * 128, n0 = blockIdx.x * 128;
  int wm = (wave >> 1) * 64, wn = (wave & 1) * 64;
  f32x4 acc[4][4] = {};
  const u16* Ag = A + (size_t)m0 * K;
  const u16* Bg = Bt + (size_t)n0 * K;
  int klr = lane >> 3, klc = lane & 7;   // row-in-8, k-chunk

  for (int k0 = 0; k0 < K; k0 += 64) {
    if (k0) __syncthreads();             // everyone done reading prev tile
#pragma unroll
    for (int i = 0; i < 4; i++) {
      int c = wave * 4 + i;              // 16 chunks x 8 rows = 128 rows
      gload_lds16(Ag + (size_t)(c * 8 + klr) * K + k0 + (klc ^ klr) * 8, &As[c * 512]);
      gload_lds16(Bg + (size_t)(c * 8 + klr) * K + k0 + (klc ^ klr) * 8, &Bs[c * 512]);
    }
    __syncthreads();                     // drains vm/lgkm: tile visible
#pragma unroll
    for (int ks = 0; ks < 2; ks++) {
      bf16x8 af[4], bf[4];
#pragma unroll
      for (int mi = 0; mi < 4; mi++)
        af[mi] = ldfrag(&As[(wm + mi * 16 + l15) * 64 + (((ks * 4 + quad) ^ (l15 & 7)) << 3)]);
#pragma unroll
      for (int ni = 0; ni < 4; ni++)
        bf[ni] = ldfrag(&Bs[(wn + ni * 16 + l15) * 64 + (((ks * 4 + quad) ^ (l15 & 7)) << 3)]);
#pragma unroll
      for (int mi = 0; mi < 4; mi++)
#pragma unroll
        for (int ni = 0; ni < 4; ni++)
          acc[mi][ni] = MFMA_BF16(af[mi], bf[ni], acc[mi][ni]);
    }
  }
  int sec = n0 >> 10;  // uniform per block: 0=q 1=k 2=v
#pragma unroll
  for (int mi = 0; mi < 4; mi++) {
    int rowb = m0 + wm + mi * 16 + quad * 4;
#pragma unroll
    for (int ni = 0; ni < 4; ni++) {
      int col = n0 + wn + ni * 16 + l15;
      int cc = col & 1023, h = cc >> 6, d = cc & 63;
#pragma unroll
      for (int r = 0; r < 4; r++) {
        int rg = rowb + r, b = rg >> 12, s = rg & 4095;
        u16 v = f2bf(acc[mi][ni][r]);
        size_t bh = (size_t)(b * 16 + h);
        if (sec == 0)      Q [(bh * 4096 + s) * 64 + d] = v;
        else if (sec == 1) Kb[(bh * 4096 + s) * 64 + d] = v;
        else {
          int sp = (s & ~31) | (((s & 15) << 1) | ((s >> 4) & 1));
          Vt[(bh * 64 + d) * 4096 + sp] = v;
        }
      }
    }
  }
}

// ---------------- RMSNorm + RoPE, in place, 16 lanes x 4 elems per row -------
__global__ __launch_bounds__(256) void k_rms_rope(u16* __restrict__ buf,
                                                  const float* __restrict__ gamma,
                                                  const float* __restrict__ cosb,
                                                  const float* __restrict__ sinb,
                                                  float scale) {
  int rid = blockIdx.x * 16 + (threadIdx.x >> 4);  // row over B*NH*S
  int l = threadIdx.x & 15;                        // 4 elems per lane
  int s = rid & 4095;
  int d0 = l * 4;
  size_t idx = (size_t)rid * 64 + d0;
  u16x4 xv = *(const u16x4*)(buf + idx);
  float x0 = bf2f(xv.x), x1 = bf2f(xv.y), x2 = bf2f(xv.z), x3 = bf2f(xv.w);
  float ss = x0 * x0 + x1 * x1 + x2 * x2 + x3 * x3;
#pragma unroll
  for (int off = 1; off < 16; off <<= 1) ss += __shfl_xor(ss, off);
  float rms = rsqrtf(ss * (1.0f / 64.0f) + 1e-6f);
  float4 g = *(const float4*)(gamma + d0);
  float n0 = x0 * rms * g.x, n1 = x1 * rms * g.y, n2 = x2 * rms * g.z, n3 = x3 * rms * g.w;
  float p0 = __shfl_xor(n0, 8), p1 = __shfl_xor(n1, 8);
  float p2 = __shfl_xor(n2, 8), p3 = __shfl_xor(n3, 8);
  float sgn = (l < 8) ? -1.f : 1.f;
  float4 c = *(const float4*)(cosb + s * 64 + d0);
  float4 sn = *(const float4*)(sinb + s * 64 + d0);
  u16x4 o;
  o.x = f2bf((n0 * c.x + sgn * p0 * sn.x) * scale);
  o.y = f2bf((n1 * c.y + sgn * p1 * sn.y) * scale);
  o.z = f2bf((n2 * c.z + sgn * p2 * sn.z) * scale);
  o.w = f2bf((n3 * c.w + sgn * p3 * sn.w) * scale);
  *(u16x4*)(buf + idx) = o;
}

// ---------------- causal flash attention -----------------------------------
// Q,K: [bh][s][d] bf16 ; Vt: [bh][d][s'] bf16 (s-interleaved, see k_gemm_qkv)
// Round-11 = round-10's plan with the register math fixed:
//   256-row tile, 4 waves x 64 q-rows, COLUMN-HALF SPLIT (round-4 trick):
//   S computed 64 cols at a time -> sa[4][4] = 64 regs (not 128). Peak live
//   ~210 < the 256-reg cap of __launch_bounds__(256,2) -> no spill (round
//   10's 368 MB scratch traffic was exactly this overflow). P[:,0:64] only
//   multiplies V rows 0:64 (PV chunks 0,1), P[:,64:128] only rows 64:128
//   (chunks 2,3); oacc accumulates across halves.
//   K double-buffered; V SINGLE-buffered with counted-vmcnt B2 (T4): issue
//   V[j] first, then K[j+1]; before PV half 0 wait vmcnt(4) -- the 4 oldest
//   (V) retire, K[j+1] stays in flight across the barrier (last iter:
//   vmcnt(0)). LDS = 32+16+20 = 68 KB -> 2 blocks/CU = 2 waves/SIMD.
//   Complementary tiles (15-t, t): every block exactly 34 k-iters.
// FIXED-MAX softmax: |score|*log2e/8 < 47 provably; shift folded into QK^T
// accumulator init; row-sum via ones-MFMA; packed-P via v_cvt_pk_bf16_f32
// with pre-interleaved V.
__device__ __forceinline__ void stage_k(const u16* Kg0, int kj, u16* Kbuf,
                                        int wave, int klr, int klc) {
  const u16* Kg = Kg0 + (size_t)kj * 128 * 64;
#pragma unroll
  for (int i = 0; i < 4; i++) {
    int c = wave * 4 + i;
    gload_lds16(Kg + (size_t)(c * 8 + klr) * 64 + (klc ^ klr) * 8, Kbuf + c * 512);
  }
}
__device__ __forceinline__ void stage_v(const u16* Vg0, int kj, u16* Vbuf,
                                        int wave, int quad, int l15) {
  const u16* Vg = Vg0 + kj * 128;
#pragma unroll
  for (int i = 0; i < 4; i++) {
    int c = wave * 4 + i;
    int vr = c * 4 + quad;
    gload_lds16(Vg + (size_t)vr * 4096 + (l15 ^ (vr & 15)) * 8, Vbuf + c * 512);
  }
}

__global__ __launch_bounds__(256, 2) void k_attn(const u16* __restrict__ Qb,
                                                 const u16* __restrict__ Kg_all,
                                                 const u16* __restrict__ Vtb,
                                                 u16* __restrict__ Ob) {
  __shared__ u16 Ks[2][128 * 64];   // 32 KB (double buffer)
  __shared__ u16 Vts[64 * 128];     // 16 KB (single buffer, counted-vmcnt B2)
  __shared__ u16 Ps[4][64 * 40];    // 20 KB, wave-private, stride 40
  const int PSTR = 40;
  int t = blockIdx.x, bhi = blockIdx.y;
  int tid = threadIdx.x, wave = tid >> 6, lane = tid & 63, quad = lane >> 4, l15 = lane & 15;
  const u16* Kg0 = Kg_all + (size_t)bhi * 4096 * 64;
  const u16* Vg0 = Vtb + (size_t)bhi * 64 * 4096;
  u16* Pw = Ps[wave];
  int klr = lane >> 3, klc = lane & 7;
  int b = bhi >> 4, h = bhi & 15;

  u16x8 ou;
#pragma unroll
  for (int i = 0; i < 8; i++) ou[i] = 0x3F80;       // bf16 1.0
  bf16x8 ones = __builtin_bit_cast(bf16x8, ou);
  const f32x4 minit = {-47.f, -47.f, -47.f, -47.f}; // fixed softmax max

#pragma unroll 1
  for (int tt = 0; tt < 2; tt++) {
    int qi = (tt == 0) ? (15 - t) : t;   // 256-row tile index, 0..15
    const u16* Qg = Qb + ((size_t)bhi * 4096 + qi * 256) * 64;
    bf16x8 aq[4][2];
#pragma unroll
    for (int mi = 0; mi < 4; mi++)
#pragma unroll
      for (int ks = 0; ks < 2; ks++)
        aq[mi][ks] = ldfrag(Qg + (size_t)(wave * 64 + mi * 16 + l15) * 64 + ks * 32 + quad * 8);
    f32x4 oacc[4][4] = {};
    f32x4 lacc[4] = {};

    if (tt) __builtin_amdgcn_s_barrier();  // all waves done with prev-tile buffers
    stage_k(Kg0, 0, Ks[0], wave, klr, klc);
    int kjmax = 2 * qi + 1;

#pragma unroll 1
    for (int kj = 0; kj <= kjmax; kj++) {
      int cur = kj & 1;
      // B1: drain K[kj] (issued a full iter ago; only K outstanding here),
      // barrier -> K[cur] visible to all, V buffer free (PV of kj-1 done).
      asm volatile("s_waitcnt vmcnt(0)" ::: "memory");
      __builtin_amdgcn_s_barrier();
      stage_v(Vg0, kj, Vts, wave, quad, l15);     // V FIRST (oldest in queue)
      asm volatile("" ::: "memory");              // pin issue order V -> K
      if (kj < kjmax)
        stage_k(Kg0, kj + 1, Ks[cur ^ 1], wave, klr, klc);
#pragma unroll
      for (int hf = 0; hf < 2; hf++) {
        // S half: 64 q-rows x k-cols [hf*64, hf*64+64), shifted by -47
        f32x4 sa[4][4];
#pragma unroll
        for (int mi = 0; mi < 4; mi++)
#pragma unroll
          for (int nbl = 0; nbl < 4; nbl++) sa[mi][nbl] = minit;
        __builtin_amdgcn_s_setprio(1);
#pragma unroll
        for (int ks = 0; ks < 2; ks++) {
#pragma unroll
          for (int nbl = 0; nbl < 4; nbl++) {
            int nb = hf * 4 + nbl;
            bf16x8 bk = ldfrag(&Ks[cur][(nb * 16 + l15) * 64 + (((ks * 4 + quad) ^ (l15 & 7)) << 3)]);
#pragma unroll
            for (int mi = 0; mi < 4; mi++)
              sa[mi][nbl] = MFMA_BF16(aq[mi][ks], bk, sa[mi][nbl]);
          }
        }
        __builtin_amdgcn_s_setprio(0);
        if (kj >= 2 * qi) {  // causal mask on the two diagonal-band k-blocks
          int d128 = (kj - 2 * qi) * 128;
#pragma unroll
          for (int mi = 0; mi < 4; mi++)
#pragma unroll
            for (int nbl = 0; nbl < 4; nbl++)
#pragma unroll
              for (int r = 0; r < 4; r++) {
                int rowi = wave * 64 + mi * 16 + quad * 4 + r;
                int coli = (hf * 4 + nbl) * 16 + l15;
                if (coli > rowi - d128) sa[mi][nbl][r] = -1e30f;
              }
        }
        // p = exp2(s - 47); no max tracking, no rescale
#pragma unroll
        for (int mi = 0; mi < 4; mi++)
#pragma unroll
          for (int nbl = 0; nbl < 4; nbl++)
#pragma unroll
            for (int r = 0; r < 4; r++)
              sa[mi][nbl][r] = fexp2(sa[mi][nbl][r]);
        if (hf == 0) {
          // B2: wait only for the 4 oldest loads (= our V); K[kj+1] stays
          // in flight across the barrier. Last iter: nothing else queued.
          if (kj < kjmax) asm volatile("s_waitcnt vmcnt(4)" ::: "memory");
          else            asm volatile("s_waitcnt vmcnt(0)" ::: "memory");
          __builtin_amdgcn_s_barrier();
        }
        // O += P_half V_half: k-chunks ks = hf*2 + {0,1}
#pragma unroll
        for (int ksl = 0; ksl < 2; ksl++) {
          int ks = hf * 2 + ksl;
          bf16x8 ap[4];
#pragma unroll
          for (int mi = 0; mi < 4; mi++) {
#pragma unroll
            for (int r = 0; r < 4; r++) {
              int prow = mi * 16 + quad * 4 + r;
              float lo = sa[mi][2 * ksl][r], hi = sa[mi][2 * ksl + 1][r];
              uint32_t pk;
              asm("v_cvt_pk_bf16_f32 %0, %1, %2" : "=v"(pk) : "v"(lo), "v"(hi));
              *(uint32_t*)&Pw[prow * PSTR + 2 * l15] = pk;
            }
            ap[mi] = ldfrag(&Pw[(mi * 16 + l15) * PSTR + quad * 8]);
          }
          __builtin_amdgcn_s_setprio(1);
#pragma unroll
          for (int oni = 0; oni < 4; oni++) {
            bf16x8 bv = ldfrag(&Vts[(oni * 16 + l15) * 128 + (((ks * 4 + quad) ^ l15) << 3)]);
#pragma unroll
            for (int mi = 0; mi < 4; mi++)
              oacc[mi][oni] = MFMA_BF16(ap[mi], bv, oacc[mi][oni]);
          }
#pragma unroll
          for (int mi = 0; mi < 4; mi++)
            lacc[mi] = MFMA_BF16(ap[mi], ones, lacc[mi]);
          __builtin_amdgcn_s_setprio(0);
        }
      }
    }
    // epilogue: O tile to global (normalize by row sum)
#pragma unroll
    for (int mi = 0; mi < 4; mi++)
#pragma unroll
      for (int oni = 0; oni < 4; oni++)
#pragma unroll
        for (int r = 0; r < 4; r++) {
          float v = oacc[mi][oni][r] / lacc[mi][r];
          int srow = qi * 256 + wave * 64 + mi * 16 + quad * 4 + r;
          int d = oni * 16 + l15;
          Ob[((size_t)(b * 4096 + srow)) * 1024 + h * 64 + d] = f2bf(v);
        }
  }
}

// ---------------- out GEMM: A(8192x1024) @ Wot(1024x1024)^T -> fp32 ----------
// BK=64 single-buffer swizzled, same as k_gemm_qkv.
__global__ __launch_bounds__(256) void k_gemm_out(const u16* __restrict__ A,
                                                  const u16* __restrict__ Bt,
                                                  float* __restrict__ C) {
  const int K = 1024, N = 1024;
  __shared__ u16 As[128 * 64];
  __shared__ u16 Bs[128 * 64];
  int tid = threadIdx.x;
  int wave = tid >> 6, lane = tid & 63, quad = lane >> 4, l15 = lane & 15;
  int m0 = blockIdx.y * 128, n0 = blockIdx.x * 128;
  int wm = (wave >> 1) * 64, wn = (wave & 1) * 64;
  f32x4 acc[4][4] = {};
  const u16* Ag = A + (size_t)m0 * K;
  const u16* Bg = Bt + (size_t)n0 * K;
  int klr = lane >> 3, klc = lane & 7;

  for (int k0 = 0; k0 < K; k0 += 64) {
    if (k0) __syncthreads();
#pragma unroll
    for (int i = 0; i < 4; i++) {
      int c = wave * 4 + i;
      gload_lds16(Ag + (size_t)(c * 8 + klr) * K + k0 + (klc ^ klr) * 8, &As[c * 512]);
      gload_lds16(Bg + (size_t)(c * 8 + klr) * K + k0 + (klc ^ klr) * 8, &Bs[c * 512]);
    }
    __syncthreads();
#pragma unroll
    for (int ks = 0; ks < 2; ks++) {
      bf16x8 af[4], bf[4];
#pragma unroll
      for (int mi = 0; mi < 4; mi++)
        af[mi] = ldfrag(&As[(wm + mi * 16 + l15) * 64 + (((ks * 4 + quad) ^ (l15 & 7)) << 3)]);
#pragma unroll
      for (int ni = 0; ni < 4; ni++)
        bf[ni] = ldfrag(&Bs[(wn + ni * 16 + l15) * 64 + (((ks * 4 + quad) ^ (l15 & 7)) << 3)]);
#pragma unroll
      for (int mi = 0; mi < 4; mi++)
#pragma unroll
        for (int ni = 0; ni < 4; ni++)
          acc[mi][ni] = MFMA_BF16(af[mi], bf[ni], acc[mi][ni]);
    }
  }
#pragma unroll
  for (int mi = 0; mi < 4; mi++) {
    int rowb = m0 + wm + mi * 16 + quad * 4;
#pragma unroll
    for (int ni = 0; ni < 4; ni++) {
      int col = n0 + wn + ni * 16 + l15;
#pragma unroll
      for (int r = 0; r < 4; r++)
        C[(size_t)(rowb + r) * N + col] = acc[mi][ni][r];
    }
  }
}

extern "C" void kernel_launch(void* const* d_in, const int* in_sizes, int n_in,
                              void* d_out, int out_size, void* d_ws, size_t ws_size,
                              hipStream_t stream) {
  (void)in_sizes; (void)n_in; (void)out_size; (void)ws_size;
  const float* hs   = (const float*)d_in[0];  // (2,4096,1024)
  const float* cosb = (const float*)d_in[1];  // (1,4096,64)
  const float* sinb = (const float*)d_in[2];
  const float* wqkv = (const float*)d_in[3];  // (1024,3072)
  const float* wo   = (const float*)d_in[4];  // (1024,1024)
  const float* gq   = (const float*)d_in[5];
  const float* gk   = (const float*)d_in[6];
  float* out = (float*)d_out;

  char* ws = (char*)d_ws;
  u16* Xb    = (u16*)(ws);              // 16,777,216 B
  u16* Wqkvt = (u16*)(ws + 16777216);   //  6,291,456 B
  u16* Wot   = (u16*)(ws + 23068672);   //  2,097,152 B
  u16* Qb    = (u16*)(ws + 25165824);   // 16,777,216 B
  u16* Kb    = (u16*)(ws + 41943040);   // 16,777,216 B
  u16* Vtb   = (u16*)(ws + 58720256);   // 16,777,216 B
  u16* Ab    = (u16*)(ws + 75497472);   // 16,777,216 B  (total ~92.3 MB)

  k_f32_to_bf16<<<8192, 256, 0, stream>>>(hs, Xb, 8388608);
  k_transpose_bf16<<<dim3(96, 32), dim3(32, 8), 0, stream>>>(wqkv, Wqkvt, 1024, 3072);
  k_transpose_bf16<<<dim3(32, 32), dim3(32, 8), 0, stream>>>(wo, Wot, 1024, 1024);
  k_gemm_qkv<<<dim3(24, 64), 256, 0, stream>>>(Xb, Wqkvt, Qb, Kb, Vtb);
  // Q scaled by 1/sqrt(hd) * log2(e): softmax runs in base-2 domain
  k_rms_rope<<<8192, 256, 0, stream>>>(Qb, gq, cosb, sinb, 0.18033688011112042f);
  k_rms_rope<<<8192, 256, 0, stream>>>(Kb, gk, cosb, sinb, 1.0f);
  k_attn<<<dim3(8, 32), 256, 0, stream>>>(Qb, Kb, Vtb, Ab);
  k_gemm_out<<<dim3(8, 64), 256, 0, stream>>>(Ab, Wot, out);
}

// Round 12
// 296.890 us; speedup vs baseline: 1.6635x; 1.2611x over previous
//
#include <hip/hip_runtime.h>
#include <stdint.h>

typedef unsigned short u16;
typedef __attribute__((ext_vector_type(8))) u16   u16x8;
typedef __attribute__((ext_vector_type(4))) u16   u16x4;
typedef __attribute__((ext_vector_type(8))) __bf16 bf16x8;
typedef __attribute__((ext_vector_type(4))) float  f32x4;

__device__ __forceinline__ u16 f2bf(float f) {
  union { float f; unsigned u; } x; x.f = f;
  unsigned r = x.u + 0x7fffu + ((x.u >> 16) & 1u);   // RNE
  return (u16)(r >> 16);
}
__device__ __forceinline__ float bf2f(u16 h) {
  union { unsigned u; float f; } x; x.u = ((unsigned)h) << 16;
  return x.f;
}
__device__ __forceinline__ float fexp2(float x) {
#if __has_builtin(__builtin_amdgcn_exp2f)
  return __builtin_amdgcn_exp2f(x);
#else
  return __expf(x * 0.69314718055994531f);
#endif
}
// async global->LDS, 16B per lane; LDS dest = uniform base + lane*16
__device__ __forceinline__ void gload_lds16(const void* g, void* l) {
  __builtin_amdgcn_global_load_lds(
      (__attribute__((address_space(1))) void*)(void*)g,
      (__attribute__((address_space(3))) void*)l, 16, 0, 0);
}
__device__ __forceinline__ bf16x8 ldfrag(const u16* p) {
  return __builtin_bit_cast(bf16x8, *(const u16x8*)p);
}
#define MFMA_BF16(a, b, c) __builtin_amdgcn_mfma_f32_16x16x32_bf16(a, b, c, 0, 0, 0)

// ---------------- elementwise fp32 -> bf16 ----------------
__global__ __launch_bounds__(256) void k_f32_to_bf16(const float* __restrict__ in,
                                                     u16* __restrict__ out, int n) {
  int i = (blockIdx.x * 256 + threadIdx.x) * 4;
  if (i >= n) return;
  float4 v = *(const float4*)(in + i);
  u16x4 o; o.x = f2bf(v.x); o.y = f2bf(v.y); o.z = f2bf(v.z); o.w = f2bf(v.w);
  *(u16x4*)(out + i) = o;
}

// ---------------- transpose fp32 (R x C) -> bf16 (C x R) ----------------
__global__ __launch_bounds__(256) void k_transpose_bf16(const float* __restrict__ in,
                                                        u16* __restrict__ out,
                                                        int R, int C) {
  __shared__ float tile[32][33];
  int c0 = blockIdx.x * 32, r0 = blockIdx.y * 32;
  int tx = threadIdx.x, ty = threadIdx.y;  // block (32,8)
#pragma unroll
  for (int i = 0; i < 32; i += 8)
    tile[ty + i][tx] = in[(size_t)(r0 + ty + i) * C + c0 + tx];
  __syncthreads();
#pragma unroll
  for (int i = 0; i < 32; i += 8)
    out[(size_t)(c0 + ty + i) * R + r0 + tx] = f2bf(tile[tx][ty + i]);
}

// ---------------- QKV GEMM + FUSED RMSNorm/RoPE epilogue --------------------
// A(8192x1024) @ Wt(3072x1024)^T. BK=64, single 32KB buffer, 2-barrier loop,
// XOR-swizzled [128][64] tiles (round 8).
// Round-12 fusion: a block's acc tile holds COMPLETE heads -- for a fixed
// output row, all 64 d of a head live in one wave: d = ni*16 + l15
// (ni=0..3, 16 lanes). So RMSNorm's sum-of-squares = 4 in-reg squares +
// 4-step 16-wide shfl_xor; RoPE partner d+-32 = ni^2 on the SAME lane.
// Q/K are normalized+roped+scaled here from fp32 acc (more accurate than
// the old bf16 round-trip); the two k_rms_rope launches are deleted.
// Q pre-scaled by 1/sqrt(hd)*log2(e) -> attn softmax runs in base-2 domain.
// V -> transposed + s-interleaved: Vt[bh][d][s'], s' = (s&~31)|((s&15)<<1)
// |((s>>4)&1) -- matches k_attn's packed-P column layout (dot-order perm).
__global__ __launch_bounds__(256) void k_gemm_qkv(const u16* __restrict__ A,
                                                  const u16* __restrict__ Bt,
                                                  u16* __restrict__ Q,
                                                  u16* __restrict__ Kb,
                                                  u16* __restrict__ Vt,
                                                  const float* __restrict__ gq,
                                                  const float* __restrict__ gk,
                                                  const float* __restrict__ cosb,
                                                  const float* __restrict__ sinb) {
  const int K = 1024;
  __shared__ u16 As[128 * 64];   // 16 KB, swizzled
  __shared__ u16 Bs[128 * 64];   // 16 KB, swizzled
  int tid = threadIdx.x;
  int wave = tid >> 6, lane = tid & 63, quad = lane >> 4, l15 = lane & 15;
  int m0 = blockIdx.y * 128, n0 = blockIdx.x * 128;
  int wm = (wave >> 1) * 64, wn = (wave & 1) * 64;
  f32x4 acc[4][4] = {};
  const u16* Ag = A + (size_t)m0 * K;
  const u16* Bg = Bt + (size_t)n0 * K;
  int klr = lane >> 3, klc = lane & 7;   // row-in-8, k-chunk

  for (int k0 = 0; k0 < K; k0 += 64) {
    if (k0) __syncthreads();             // everyone done reading prev tile
#pragma unroll
    for (int i = 0; i < 4; i++) {
      int c = wave * 4 + i;              // 16 chunks x 8 rows = 128 rows
      gload_lds16(Ag + (size_t)(c * 8 + klr) * K + k0 + (klc ^ klr) * 8, &As[c * 512]);
      gload_lds16(Bg + (size_t)(c * 8 + klr) * K + k0 + (klc ^ klr) * 8, &Bs[c * 512]);
    }
    __syncthreads();                     // drains vm/lgkm: tile visible
#pragma unroll
    for (int ks = 0; ks < 2; ks++) {
      bf16x8 af[4], bf[4];
#pragma unroll
      for (int mi = 0; mi < 4; mi++)
        af[mi] = ldfrag(&As[(wm + mi * 16 + l15) * 64 + (((ks * 4 + quad) ^ (l15 & 7)) << 3)]);
#pragma unroll
      for (int ni = 0; ni < 4; ni++)
        bf[ni] = ldfrag(&Bs[(wn + ni * 16 + l15) * 64 + (((ks * 4 + quad) ^ (l15 & 7)) << 3)]);
#pragma unroll
      for (int mi = 0; mi < 4; mi++)
#pragma unroll
        for (int ni = 0; ni < 4; ni++)
          acc[mi][ni] = MFMA_BF16(af[mi], bf[ni], acc[mi][ni]);
    }
  }
  int sec = n0 >> 10;  // uniform per block: 0=q 1=k 2=v
  if (sec < 2) {
    // fused RMSNorm + RoPE epilogue (Q gets the attn prescale folded in)
    float scl = (sec == 0) ? 0.18033688011112042f : 1.0f;  // log2(e)/8 or 1
    const float* gam = (sec == 0) ? gq : gk;
    u16* Dst = (sec == 0) ? Q : Kb;
    float g0 = gam[l15], g1 = gam[16 + l15], g2 = gam[32 + l15], g3 = gam[48 + l15];
    int h = ((n0 + wn) & 1023) >> 6;     // head index, uniform per wave
#pragma unroll
    for (int mi = 0; mi < 4; mi++) {
      int rowb = m0 + wm + mi * 16 + quad * 4;
#pragma unroll
      for (int r = 0; r < 4; r++) {
        int rg = rowb + r, b = rg >> 12, s = rg & 4095;
        float x0 = acc[mi][0][r], x1 = acc[mi][1][r];
        float x2 = acc[mi][2][r], x3 = acc[mi][3][r];
        float ssum = x0 * x0 + x1 * x1 + x2 * x2 + x3 * x3;
#pragma unroll
        for (int off = 1; off < 16; off <<= 1) ssum += __shfl_xor(ssum, off);
        float rms = rsqrtf(ssum * (1.0f / 64.0f) + 1e-6f);
        float nv0 = x0 * rms * g0, nv1 = x1 * rms * g1;
        float nv2 = x2 * rms * g2, nv3 = x3 * rms * g3;
        const float* cp = cosb + s * 64 + l15;
        const float* sp = sinb + s * 64 + l15;
        float c0 = cp[0], c1 = cp[16], c2 = cp[32], c3 = cp[48];
        float s0 = sp[0], s1 = sp[16], s2 = sp[32], s3 = sp[48];
        // rotate_half: d<32 -> -x[d+32] (partner ni^2), d>=32 -> +x[d-32]
        float o0 = (nv0 * c0 - nv2 * s0) * scl;
        float o1 = (nv1 * c1 - nv3 * s1) * scl;
        float o2 = (nv2 * c2 + nv0 * s2) * scl;
        float o3 = (nv3 * c3 + nv1 * s3) * scl;
        size_t base = ((size_t)(b * 16 + h) * 4096 + s) * 64 + l15;
        Dst[base]      = f2bf(o0);
        Dst[base + 16] = f2bf(o1);
        Dst[base + 32] = f2bf(o2);
        Dst[base + 48] = f2bf(o3);
      }
    }
  } else {
    // V path: transpose + s-interleave, unchanged
#pragma unroll
    for (int mi = 0; mi < 4; mi++) {
      int rowb = m0 + wm + mi * 16 + quad * 4;
#pragma unroll
      for (int ni = 0; ni < 4; ni++) {
        int col = n0 + wn + ni * 16 + l15;
        int cc = col & 1023, h = cc >> 6, d = cc & 63;
#pragma unroll
        for (int r = 0; r < 4; r++) {
          int rg = rowb + r, b = rg >> 12, s = rg & 4095;
          u16 v = f2bf(acc[mi][ni][r]);
          size_t bh = (size_t)(b * 16 + h);
          int sp = (s & ~31) | (((s & 15) << 1) | ((s >> 4) & 1));
          Vt[(bh * 64 + d) * 4096 + sp] = v;
        }
      }
    }
  }
}

// ---------------- causal flash attention (round-8 version, measured 110us) --
// Q,K: [bh][s][d] bf16 ; Vt: [bh][d][s'] bf16 (s-interleaved, see k_gemm_qkv)
//  * TRUE 2-STAGE PIPELINE: K AND V double-buffered; stage [j+1] right after
//    the single iter-top {s_waitcnt vmcnt(0); s_barrier}; compute on [j].
//  * PACKED P: v_cvt_pk_bf16_f32 packs two 16-col sub-blocks per u32
//    ds_write, col layout c' = (c&15)*2 + (c>>4); V pre-permuted to match.
// FIXED-MAX softmax: |score|*log2e/8 < 47 provably; shift folded into QK^T
// accumulator init; row-sum via ones-MFMA on the same bf16 P.
// LDS 75.8 KB -> 2 blocks/CU (grid 512 blocks = 2/CU, uniform 33 iters).
__device__ __forceinline__ void stage_k(const u16* Kg0, int kj, u16* Kbuf,
                                        int wave, int klr, int klc) {
  const u16* Kg = Kg0 + (size_t)kj * 128 * 64;
#pragma unroll
  for (int i = 0; i < 4; i++) {
    int c = wave * 4 + i;
    gload_lds16(Kg + (size_t)(c * 8 + klr) * 64 + (klc ^ klr) * 8, Kbuf + c * 512);
  }
}
__device__ __forceinline__ void stage_v(const u16* Vg0, int kj, u16* Vbuf,
                                        int wave, int quad, int l15) {
  const u16* Vg = Vg0 + kj * 128;
#pragma unroll
  for (int i = 0; i < 4; i++) {
    int c = wave * 4 + i;
    int vr = c * 4 + quad;
    gload_lds16(Vg + (size_t)vr * 4096 + (l15 ^ (vr & 15)) * 8, Vbuf + c * 512);
  }
}

__global__ __launch_bounds__(256, 2) void k_attn(const u16* __restrict__ Qb,
                                                 const u16* __restrict__ Kg_all,
                                                 const u16* __restrict__ Vtb,
                                                 u16* __restrict__ Ob) {
  __shared__ u16 Ks[2][128 * 64];   // 32 KB (double buffer)
  __shared__ u16 Vts[2][64 * 128];  // 32 KB (double buffer)
  __shared__ u16 Ps[4][32 * 40];    // 10 KB, wave-private, stride 40
  const int PSTR = 40;
  int t = blockIdx.x, bhi = blockIdx.y;
  int tid = threadIdx.x, wave = tid >> 6, lane = tid & 63, quad = lane >> 4, l15 = lane & 15;
  const u16* Kg0 = Kg_all + (size_t)bhi * 4096 * 64;
  const u16* Vg0 = Vtb + (size_t)bhi * 64 * 4096;
  u16* Pw = Ps[wave];
  int klr = lane >> 3, klc = lane & 7;
  int b = bhi >> 4, h = bhi & 15;

  u16x8 ou;
#pragma unroll
  for (int i = 0; i < 8; i++) ou[i] = 0x3F80;       // bf16 1.0
  bf16x8 ones = __builtin_bit_cast(bf16x8, ou);
  const f32x4 minit = {-47.f, -47.f, -47.f, -47.f}; // fixed softmax max

#pragma unroll 1
  for (int tt = 0; tt < 2; tt++) {
    int qi = (tt == 0) ? (31 - t) : t;   // 128-row tile index, 0..31
    const u16* Qg = Qb + ((size_t)bhi * 4096 + qi * 128) * 64;
    bf16x8 aq[2][2];
#pragma unroll
    for (int mi = 0; mi < 2; mi++)
#pragma unroll
      for (int ks = 0; ks < 2; ks++)
        aq[mi][ks] = ldfrag(Qg + (size_t)(wave * 32 + mi * 16 + l15) * 64 + ks * 32 + quad * 8);
    f32x4 oacc[2][4] = {};
    f32x4 lacc[2] = {};

    if (tt) __builtin_amdgcn_s_barrier();  // all waves done reading prev-tile buffers
    stage_k(Kg0, 0, Ks[0], wave, klr, klc);
    stage_v(Vg0, 0, Vts[0], wave, quad, l15);

#pragma unroll 1
    for (int kj = 0; kj <= qi; kj++) {
      int cur = kj & 1;
      // single per-iter sync: drain own loads (issued a full iter ago),
      // then barrier -> everyone's K[cur]/V[cur] visible, everyone done
      // reading buffers [cur^1] so they can be restaged.
      asm volatile("s_waitcnt vmcnt(0)" ::: "memory");
      __builtin_amdgcn_s_barrier();
      if (kj < qi) {
        stage_k(Kg0, kj + 1, Ks[cur ^ 1], wave, klr, klc);
        stage_v(Vg0, kj + 1, Vts[cur ^ 1], wave, quad, l15);
      }
      // S = Q K^T - 47 (q pre-scaled by log2e/8 -> base-2 domain)
      f32x4 sa[2][8];
#pragma unroll
      for (int mi = 0; mi < 2; mi++)
#pragma unroll
        for (int nb = 0; nb < 8; nb++) sa[mi][nb] = minit;
      __builtin_amdgcn_s_setprio(1);
#pragma unroll
      for (int ks = 0; ks < 2; ks++) {
#pragma unroll
        for (int nb = 0; nb < 8; nb++) {
          bf16x8 bk = ldfrag(&Ks[cur][(nb * 16 + l15) * 64 + (((ks * 4 + quad) ^ (l15 & 7)) << 3)]);
          sa[0][nb] = MFMA_BF16(aq[0][ks], bk, sa[0][nb]);
          sa[1][nb] = MFMA_BF16(aq[1][ks], bk, sa[1][nb]);
        }
      }
      __builtin_amdgcn_s_setprio(0);
      if (kj == qi) {  // causal mask on diagonal tile (local coords)
#pragma unroll
        for (int mi = 0; mi < 2; mi++)
#pragma unroll
          for (int nb = 0; nb < 8; nb++)
#pragma unroll
            for (int r = 0; r < 4; r++) {
              int rowi = wave * 32 + mi * 16 + quad * 4 + r;
              int coli = nb * 16 + l15;
              if (coli > rowi) sa[mi][nb][r] = -1e30f;
            }
      }
      // p = exp2(s - 47); no max tracking, no rescale
#pragma unroll
      for (int mi = 0; mi < 2; mi++)
#pragma unroll
        for (int nb = 0; nb < 8; nb++)
#pragma unroll
          for (int r = 0; r < 4; r++)
            sa[mi][nb][r] = fexp2(sa[mi][nb][r]);
      // O += P V, 32-wide k chunks; packed-P via wave-private LDS (no barrier)
#pragma unroll
      for (int ks = 0; ks < 4; ks++) {
        bf16x8 ap[2];
#pragma unroll
        for (int mi = 0; mi < 2; mi++) {
#pragma unroll
          for (int r = 0; r < 4; r++) {
            int prow = mi * 16 + quad * 4 + r;
            float lo = sa[mi][2 * ks][r], hi = sa[mi][2 * ks + 1][r];
            uint32_t pk;
            asm("v_cvt_pk_bf16_f32 %0, %1, %2" : "=v"(pk) : "v"(lo), "v"(hi));
            *(uint32_t*)&Pw[prow * PSTR + 2 * l15] = pk;
          }
          ap[mi] = ldfrag(&Pw[(mi * 16 + l15) * PSTR + quad * 8]);
        }
        __builtin_amdgcn_s_setprio(1);
#pragma unroll
        for (int oni = 0; oni < 4; oni++) {
          bf16x8 bv = ldfrag(&Vts[cur][(oni * 16 + l15) * 128 + (((ks * 4 + quad) ^ l15) << 3)]);
          oacc[0][oni] = MFMA_BF16(ap[0], bv, oacc[0][oni]);
          oacc[1][oni] = MFMA_BF16(ap[1], bv, oacc[1][oni]);
        }
        lacc[0] = MFMA_BF16(ap[0], ones, lacc[0]);
        lacc[1] = MFMA_BF16(ap[1], ones, lacc[1]);
        __builtin_amdgcn_s_setprio(0);
      }
    }
    // epilogue: O tile to global (normalize by row sum)
#pragma unroll
    for (int mi = 0; mi < 2; mi++)
#pragma unroll
      for (int oni = 0; oni < 4; oni++)
#pragma unroll
        for (int r = 0; r < 4; r++) {
          float v = oacc[mi][oni][r] / lacc[mi][r];
          int srow = qi * 128 + wave * 32 + mi * 16 + quad * 4 + r;
          int d = oni * 16 + l15;
          Ob[((size_t)(b * 4096 + srow)) * 1024 + h * 64 + d] = f2bf(v);
        }
  }
}

// ---------------- out GEMM: A(8192x1024) @ Wot(1024x1024)^T -> fp32 ----------
// BK=64 single-buffer swizzled, same as k_gemm_qkv.
__global__ __launch_bounds__(256) void k_gemm_out(const u16* __restrict__ A,
                                                  const u16* __restrict__ Bt,
                                                  float* __restrict__ C) {
  const int K = 1024, N = 1024;
  __shared__ u16 As[128 * 64];
  __shared__ u16 Bs[128 * 64];
  int tid = threadIdx.x;
  int wave = tid >> 6, lane = tid & 63, quad = lane >> 4, l15 = lane & 15;
  int m0 = blockIdx.y * 128, n0 = blockIdx.x * 128;
  int wm = (wave >> 1) * 64, wn = (wave & 1) * 64;
  f32x4 acc[4][4] = {};
  const u16* Ag = A + (size_t)m0 * K;
  const u16* Bg = Bt + (size_t)n0 * K;
  int klr = lane >> 3, klc = lane & 7;

  for (int k0 = 0; k0 < K; k0 += 64) {
    if (k0) __syncthreads();
#pragma unroll
    for (int i = 0; i < 4; i++) {
      int c = wave * 4 + i;
      gload_lds16(Ag + (size_t)(c * 8 + klr) * K + k0 + (klc ^ klr) * 8, &As[c * 512]);
      gload_lds16(Bg + (size_t)(c * 8 + klr) * K + k0 + (klc ^ klr) * 8, &Bs[c * 512]);
    }
    __syncthreads();
#pragma unroll
    for (int ks = 0; ks < 2; ks++) {
      bf16x8 af[4], bf[4];
#pragma unroll
      for (int mi = 0; mi < 4; mi++)
        af[mi] = ldfrag(&As[(wm + mi * 16 + l15) * 64 + (((ks * 4 + quad) ^ (l15 & 7)) << 3)]);
#pragma unroll
      for (int ni = 0; ni < 4; ni++)
        bf[ni] = ldfrag(&Bs[(wn + ni * 16 + l15) * 64 + (((ks * 4 + quad) ^ (l15 & 7)) << 3)]);
#pragma unroll
      for (int mi = 0; mi < 4; mi++)
#pragma unroll
        for (int ni = 0; ni < 4; ni++)
          acc[mi][ni] = MFMA_BF16(af[mi], bf[ni], acc[mi][ni]);
    }
  }
#pragma unroll
  for (int mi = 0; mi < 4; mi++) {
    int rowb = m0 + wm + mi * 16 + quad * 4;
#pragma unroll
    for (int ni = 0; ni < 4; ni++) {
      int col = n0 + wn + ni * 16 + l15;
#pragma unroll
      for (int r = 0; r < 4; r++)
        C[(size_t)(rowb + r) * N + col] = acc[mi][ni][r];
    }
  }
}

extern "C" void kernel_launch(void* const* d_in, const int* in_sizes, int n_in,
                              void* d_out, int out_size, void* d_ws, size_t ws_size,
                              hipStream_t stream) {
  (void)in_sizes; (void)n_in; (void)out_size; (void)ws_size;
  const float* hs   = (const float*)d_in[0];  // (2,4096,1024)
  const float* cosb = (const float*)d_in[1];  // (1,4096,64)
  const float* sinb = (const float*)d_in[2];
  const float* wqkv = (const float*)d_in[3];  // (1024,3072)
  const float* wo   = (const float*)d_in[4];  // (1024,1024)
  const float* gq   = (const float*)d_in[5];
  const float* gk   = (const float*)d_in[6];
  float* out = (float*)d_out;

  char* ws = (char*)d_ws;
  u16* Xb    = (u16*)(ws);              // 16,777,216 B
  u16* Wqkvt = (u16*)(ws + 16777216);   //  6,291,456 B
  u16* Wot   = (u16*)(ws + 23068672);   //  2,097,152 B
  u16* Qb    = (u16*)(ws + 25165824);   // 16,777,216 B
  u16* Kb    = (u16*)(ws + 41943040);   // 16,777,216 B
  u16* Vtb   = (u16*)(ws + 58720256);   // 16,777,216 B
  u16* Ab    = (u16*)(ws + 75497472);   // 16,777,216 B  (total ~92.3 MB)

  k_f32_to_bf16<<<8192, 256, 0, stream>>>(hs, Xb, 8388608);
  k_transpose_bf16<<<dim3(96, 32), dim3(32, 8), 0, stream>>>(wqkv, Wqkvt, 1024, 3072);
  k_transpose_bf16<<<dim3(32, 32), dim3(32, 8), 0, stream>>>(wo, Wot, 1024, 1024);
  // QKV GEMM with fused RMSNorm+RoPE (Q also gets log2e/8 prescale)
  k_gemm_qkv<<<dim3(24, 64), 256, 0, stream>>>(Xb, Wqkvt, Qb, Kb, Vtb,
                                               gq, gk, cosb, sinb);
  k_attn<<<dim3(16, 32), 256, 0, stream>>>(Qb, Kb, Vtb, Ab);
  k_gemm_out<<<dim3(8, 64), 256, 0, stream>>>(Ab, Wot, out);
}